// Round 1
// baseline (350.241 us; speedup 1.0000x reference)
//
#include <hip/hip_runtime.h>
#include <math.h>

#define N_NODES 1000
#define T_STEPS 32
#define H_DIM   128
#define E_EDGES 16000
#define ED_DIM  16
#define G_GRAPHS 32
#define EP_EDGES (E_EDGES + N_NODES)
#define NEG_SLOPE 0.2f
#define LN_EPS 1e-5f

// ---------- prep: transpose conv_w [O][I][K] -> wt[k][i][o] (coalesced per-o reads) ----------
__global__ void k_prep_w(const float* __restrict__ conv_w, float* __restrict__ wt) {
    int i = blockIdx.x * 256 + threadIdx.x;
    if (i >= 128 * 128 * 3) return;
    int k = i % 3;
    int hi = (i / 3) % 128;
    int o = i / (3 * 128);
    wt[(k * 128 + hi) * 128 + o] = conv_w[i];
}

// ---------- CSR by dst: counts (int atomics, deterministic) ----------
__global__ void k_count(const int* __restrict__ dst, int* __restrict__ cnt) {
    int e = blockIdx.x * 256 + threadIdx.x;
    if (e < E_EDGES) atomicAdd(&cnt[dst[e]], 1);
}

// ---------- exclusive scan over N=1000 counts (single block) ----------
__global__ void k_scan(const int* __restrict__ cnt, int* __restrict__ offs) {
    __shared__ int sm[1024];
    int t = threadIdx.x;
    sm[t] = (t < N_NODES) ? cnt[t] : 0;
    for (int s = 1; s < 1024; s <<= 1) {
        __syncthreads();
        int a = (t >= s) ? sm[t - s] : 0;
        __syncthreads();
        sm[t] += a;
    }
    __syncthreads();
    if (t < N_NODES) offs[t + 1] = sm[t];
    if (t == 0) offs[0] = 0;
}

// ---------- ordered CSR fill: one wave per node scans dst, ballot-ranked (deterministic) ----------
__global__ void k_fill(const int* __restrict__ dst, const int* __restrict__ offs,
                       int* __restrict__ csr) {
    int n = blockIdx.x;
    int lane = threadIdx.x;  // 64
    int pos = offs[n];
    for (int b = 0; b < E_EDGES; b += 64) {
        int e = b + lane;
        bool m = (e < E_EDGES) && (dst[e] == n);
        unsigned long long mask = __ballot(m);
        if (m) {
            int rank = __popcll(mask & ((1ULL << lane) - 1ULL));
            csr[pos + rank] = e;
        }
        pos += __popcll(mask);
    }
}

// ---------- loop_attr[n] = mean of incoming edge_attr ----------
__global__ void k_loopattr(const float* __restrict__ edge_attr, const int* __restrict__ csr,
                           const int* __restrict__ offs, const int* __restrict__ cnt,
                           float* __restrict__ loop_attr) {
    int n = blockIdx.x;
    int lane = threadIdx.x;           // 64
    int q = lane >> 4, f = lane & 15; // 4-way edge parallel over 16 channels
    int off = offs[n], deg = cnt[n];
    float a = 0.f;
    for (int i = q; i < deg; i += 4) a += edge_attr[csr[off + i] * ED_DIM + f];
    a += __shfl_xor(a, 16);
    a += __shfl_xor(a, 32);
    if (lane < 16) loop_attr[n * ED_DIM + lane] = a / fmaxf((float)deg, 1.0f);
}

// ---------- ee[e][h] = ea[e] @ We, for all E+N edges ----------
__global__ void k_ee(const float* __restrict__ edge_attr, const float* __restrict__ loop_attr,
                     const float* __restrict__ We, float* __restrict__ ee) {
    int e = blockIdx.x * 2 + (threadIdx.x >> 7);
    int h = threadIdx.x & 127;
    if (e >= EP_EDGES) return;
    const float* ea = (e < E_EDGES) ? &edge_attr[e * ED_DIM]
                                    : &loop_attr[(e - E_EDGES) * ED_DIM];
    float acc = 0.f;
#pragma unroll
    for (int f = 0; f < ED_DIM; ++f) acc += ea[f] * We[f * H_DIM + h];
    ee[e * H_DIM + h] = acc;
}

// ---------- fused: conv1d(T,'SAME') + residual + LN1 + gl/gr GEMMs, one block per node ----------
__global__ __launch_bounds__(256) void k_temporal(
    const float* __restrict__ x, const float* __restrict__ wt, const float* __restrict__ conv_b,
    const float* __restrict__ ln1_g, const float* __restrict__ ln1_b,
    const float* __restrict__ Wl, const float* __restrict__ Wr,
    float* __restrict__ x1, float* __restrict__ gl, float* __restrict__ gr) {
    __shared__ float xs[T_STEPS][H_DIM];
    __shared__ float yb[T_STEPS][H_DIM];
    __shared__ float x1b[T_STEPS][H_DIM];
    int n = blockIdx.x;
    int tid = threadIdx.x;

    const float4* xsrc = (const float4*)&x[n * T_STEPS * H_DIM];
    float4* xdst = (float4*)&xs[0][0];
    for (int i = tid; i < T_STEPS * H_DIM / 4; i += 256) xdst[i] = xsrc[i];
    __syncthreads();

    int o = tid & 127, th = tid >> 7;  // thread owns channel o, t-range [th*16, th*16+16)
    float acc[16];
    float bo = conv_b[o];
#pragma unroll
    for (int j = 0; j < 16; ++j) acc[j] = bo;
    for (int hi = 0; hi < H_DIM; ++hi) {
        float w0 = wt[(0 * 128 + hi) * 128 + o];
        float w1 = wt[(1 * 128 + hi) * 128 + o];
        float w2 = wt[(2 * 128 + hi) * 128 + o];
        float xv[18];
#pragma unroll
        for (int u = 0; u < 18; ++u) {
            int tt = th * 16 + u - 1;
            xv[u] = (tt >= 0 && tt < T_STEPS) ? xs[tt][hi] : 0.f;
        }
#pragma unroll
        for (int j = 0; j < 16; ++j) acc[j] += w0 * xv[j] + w1 * xv[j + 1] + w2 * xv[j + 2];
    }
#pragma unroll
    for (int j = 0; j < 16; ++j) yb[th * 16 + j][o] = acc[j];
    __syncthreads();

    // LN1 over H: 4 waves, wave handles t = wave, wave+4, ...
    int wave = tid >> 6, lane = tid & 63;
    for (int t = wave; t < T_STEPS; t += 4) {
        float r0 = xs[t][lane] + yb[t][lane];
        float r1 = xs[t][lane + 64] + yb[t][lane + 64];
        float s = r0 + r1, s2 = r0 * r0 + r1 * r1;
#pragma unroll
        for (int mm = 1; mm < 64; mm <<= 1) {
            s += __shfl_xor(s, mm);
            s2 += __shfl_xor(s2, mm);
        }
        float mean = s * (1.f / 128.f);
        float var = s2 * (1.f / 128.f) - mean * mean;
        float rs = rsqrtf(var + LN_EPS);
        float o0 = (r0 - mean) * rs * ln1_g[lane] + ln1_b[lane];
        float o1 = (r1 - mean) * rs * ln1_g[lane + 64] + ln1_b[lane + 64];
        x1b[t][lane] = o0;
        x1b[t][lane + 64] = o1;
        x1[(n * T_STEPS + t) * H_DIM + lane] = o0;
        x1[(n * T_STEPS + t) * H_DIM + lane + 64] = o1;
    }
    __syncthreads();

    // gl/gr: out channel o, 16 t's per thread
    float accl[16], accr[16];
#pragma unroll
    for (int j = 0; j < 16; ++j) { accl[j] = 0.f; accr[j] = 0.f; }
    for (int hi = 0; hi < H_DIM; ++hi) {
        float wl = Wl[hi * H_DIM + o];
        float wr = Wr[hi * H_DIM + o];
#pragma unroll
        for (int j = 0; j < 16; ++j) {
            float xv = x1b[th * 16 + j][hi];
            accl[j] += xv * wl;
            accr[j] += xv * wr;
        }
    }
#pragma unroll
    for (int j = 0; j < 16; ++j) {
        int t = th * 16 + j;
        gl[(t * N_NODES + n) * H_DIM + o] = accl[j];
        gr[(t * N_NODES + n) * H_DIM + o] = accr[j];
    }
}

// ---------- GATv2 per (node, graph): online scatter-softmax + aggregate + residual + LN2 ----------
__global__ __launch_bounds__(128) void k_gat(
    const float* __restrict__ gl, const float* __restrict__ gr, const float* __restrict__ ee,
    const int* __restrict__ src_arr, const int* __restrict__ csr,
    const int* __restrict__ offs, const int* __restrict__ cnt,
    const float* __restrict__ att, const float* __restrict__ gat_b,
    const float* __restrict__ x1, const float* __restrict__ ln2_g,
    const float* __restrict__ ln2_b, float* __restrict__ out) {
    int bid = blockIdx.x;  // n*32 + g  (consecutive blocks share node n -> ee reuse in L2)
    int n = bid >> 5;
    int g = bid & 31;
    int tid = threadIdx.x;  // k = tid>>5, d = tid&31

    float grv = gr[(g * N_NODES + n) * H_DIM + tid];
    float attv = att[tid];
    float m = -INFINITY, l = 0.f, acc = 0.f;
    int off = offs[n], deg = cnt[n];

    for (int i = 0; i <= deg; ++i) {
        int e, s;
        if (i < deg) { e = csr[off + i]; s = src_arr[e]; }
        else         { e = E_EDGES + n;  s = n; }          // self-loop last
        float glv = gl[(g * N_NODES + s) * H_DIM + tid];
        float sf = glv + grv + ee[e * H_DIM + tid];
        sf = (sf >= 0.f) ? sf : NEG_SLOPE * sf;
        float p = sf * attv;
#pragma unroll
        for (int mm = 1; mm < 32; mm <<= 1) p += __shfl_xor(p, mm);  // reduce over d in head
        float mn = fmaxf(m, p);
        float sc = __expf(m - mn);  // exp(-inf)=0 on first iter
        float w = __expf(p - mn);
        l = l * sc + w;
        acc = acc * sc + w * glv;
        m = mn;
    }
    float ov = acc / l + gat_b[tid];
    float rv = x1[(n * T_STEPS + g) * H_DIM + tid] + ov;

    // LN2 across 128 threads (2 waves)
    __shared__ float red[4];
    float s1 = rv, s2v = rv * rv;
#pragma unroll
    for (int mm = 1; mm < 64; mm <<= 1) {
        s1 += __shfl_xor(s1, mm);
        s2v += __shfl_xor(s2v, mm);
    }
    int wave = tid >> 6, lane = tid & 63;
    if (lane == 0) { red[wave * 2] = s1; red[wave * 2 + 1] = s2v; }
    __syncthreads();
    float ts = red[0] + red[2], ts2 = red[1] + red[3];
    float mean = ts * (1.f / 128.f);
    float var = ts2 * (1.f / 128.f) - mean * mean;
    float rs = rsqrtf(var + LN_EPS);
    out[(n * T_STEPS + g) * H_DIM + tid] = (rv - mean) * rs * ln2_g[tid] + ln2_b[tid];
}

extern "C" void kernel_launch(void* const* d_in, const int* in_sizes, int n_in,
                              void* d_out, int out_size, void* d_ws, size_t ws_size,
                              hipStream_t stream) {
    const float* x         = (const float*)d_in[0];
    const int*   ei        = (const int*)d_in[1];
    const float* edge_attr = (const float*)d_in[2];
    const float* conv_w    = (const float*)d_in[3];
    const float* conv_b    = (const float*)d_in[4];
    const float* ln1_g     = (const float*)d_in[5];
    const float* ln1_b     = (const float*)d_in[6];
    const float* Wl        = (const float*)d_in[7];
    const float* Wr        = (const float*)d_in[8];
    const float* We        = (const float*)d_in[9];
    const float* att       = (const float*)d_in[10];
    const float* gat_b     = (const float*)d_in[11];
    const float* ln2_g     = (const float*)d_in[12];
    const float* ln2_b     = (const float*)d_in[13];
    float* out = (float*)d_out;

    const int* src = ei;
    const int* dst = ei + E_EDGES;

    // workspace layout (floats)
    float* wt  = (float*)d_ws;                 // 49152
    float* x1  = wt + 49152;                   // 4,096,000
    float* gl  = x1 + 4096000;                 // 4,096,000
    float* gr  = gl + 4096000;                 // 4,096,000
    float* eew = gr + 4096000;                 // 2,176,000
    float* la  = eew + 2176000;                // 16,000
    int*   cnt  = (int*)(la + 16000);          // 1000
    int*   offs = cnt + 1000;                  // 1001
    int*   csr  = offs + 1001;                 // 16000

    k_prep_w<<<192, 256, 0, stream>>>(conv_w, wt);
    hipMemsetAsync(cnt, 0, N_NODES * sizeof(int), stream);
    k_count<<<(E_EDGES + 255) / 256, 256, 0, stream>>>(dst, cnt);
    k_scan<<<1, 1024, 0, stream>>>(cnt, offs);
    k_fill<<<N_NODES, 64, 0, stream>>>(dst, offs, csr);
    k_loopattr<<<N_NODES, 64, 0, stream>>>(edge_attr, csr, offs, cnt, la);
    k_ee<<<(EP_EDGES + 1) / 2, 256, 0, stream>>>(edge_attr, la, We, eew);
    k_temporal<<<N_NODES, 256, 0, stream>>>(x, wt, conv_b, ln1_g, ln1_b, Wl, Wr, x1, gl, gr);
    k_gat<<<N_NODES * G_GRAPHS, 128, 0, stream>>>(gl, gr, eew, src, csr, offs, cnt,
                                                  att, gat_b, x1, ln2_g, ln2_b, out);
}

// Round 2
// 273.418 us; speedup vs baseline: 1.2810x; 1.2810x over previous
//
#include <hip/hip_runtime.h>
#include <math.h>

#define N_NODES 1000
#define T_STEPS 32
#define H_DIM   128
#define E_EDGES 16000
#define ED_DIM  16
#define G_GRAPHS 32
#define EP_EDGES (E_EDGES + N_NODES)
#define NEG_SLOPE 0.2f
#define LN_EPS 1e-5f
#define XT_STRIDE 36   // 34 used cols padded to 36 -> row byte stride 144 = 9*16 (b128-aligned)

// ---------- prep: transpose conv_w [O][I][K] -> wt[k][i][o] (coalesced per-o reads) ----------
__global__ void k_prep_w(const float* __restrict__ conv_w, float* __restrict__ wt) {
    int i = blockIdx.x * 256 + threadIdx.x;
    if (i >= 128 * 128 * 3) return;
    int k = i % 3;
    int hi = (i / 3) % 128;
    int o = i / (3 * 128);
    wt[(k * 128 + hi) * 128 + o] = conv_w[i];
}

// ---------- CSR by dst: counts (int atomics, deterministic) ----------
__global__ void k_count(const int* __restrict__ dst, int* __restrict__ cnt) {
    int e = blockIdx.x * 256 + threadIdx.x;
    if (e < E_EDGES) atomicAdd(&cnt[dst[e]], 1);
}

// ---------- exclusive scan over N=1000 counts (single block) ----------
__global__ void k_scan(const int* __restrict__ cnt, int* __restrict__ offs) {
    __shared__ int sm[1024];
    int t = threadIdx.x;
    sm[t] = (t < N_NODES) ? cnt[t] : 0;
    for (int s = 1; s < 1024; s <<= 1) {
        __syncthreads();
        int a = (t >= s) ? sm[t - s] : 0;
        __syncthreads();
        sm[t] += a;
    }
    __syncthreads();
    if (t < N_NODES) offs[t + 1] = sm[t];
    if (t == 0) offs[0] = 0;
}

// ---------- ordered CSR fill: one wave per node scans dst, ballot-ranked (deterministic) ----------
__global__ void k_fill(const int* __restrict__ dst, const int* __restrict__ offs,
                       int* __restrict__ csr) {
    int n = blockIdx.x;
    int lane = threadIdx.x;  // 64
    int pos = offs[n];
    for (int b = 0; b < E_EDGES; b += 64) {
        int e = b + lane;
        bool m = (e < E_EDGES) && (dst[e] == n);
        unsigned long long mask = __ballot(m);
        if (m) {
            int rank = __popcll(mask & ((1ULL << lane) - 1ULL));
            csr[pos + rank] = e;
        }
        pos += __popcll(mask);
    }
}

// ---------- loop_attr[n] = mean of incoming edge_attr ----------
__global__ void k_loopattr(const float* __restrict__ edge_attr, const int* __restrict__ csr,
                           const int* __restrict__ offs, const int* __restrict__ cnt,
                           float* __restrict__ loop_attr) {
    int n = blockIdx.x;
    int lane = threadIdx.x;           // 64
    int q = lane >> 4, f = lane & 15; // 4-way edge parallel over 16 channels
    int off = offs[n], deg = cnt[n];
    float a = 0.f;
    for (int i = q; i < deg; i += 4) a += edge_attr[csr[off + i] * ED_DIM + f];
    a += __shfl_xor(a, 16);
    a += __shfl_xor(a, 32);
    if (lane < 16) loop_attr[n * ED_DIM + lane] = a / fmaxf((float)deg, 1.0f);
}

// ---------- ee[e][h] = ea[e] @ We, for all E+N edges ----------
__global__ void k_ee(const float* __restrict__ edge_attr, const float* __restrict__ loop_attr,
                     const float* __restrict__ We, float* __restrict__ ee) {
    int e = blockIdx.x * 2 + (threadIdx.x >> 7);
    int h = threadIdx.x & 127;
    if (e >= EP_EDGES) return;
    const float* ea = (e < E_EDGES) ? &edge_attr[e * ED_DIM]
                                    : &loop_attr[(e - E_EDGES) * ED_DIM];
    float acc = 0.f;
#pragma unroll
    for (int f = 0; f < ED_DIM; ++f) acc += ea[f] * We[f * H_DIM + h];
    ee[e * H_DIM + h] = acc;
}

// ---------- fused: conv1d + residual + LN1 + gl/gr GEMMs; transposed-halo LDS, one buffer ----------
__global__ __launch_bounds__(256) void k_temporal(
    const float* __restrict__ x, const float* __restrict__ wt, const float* __restrict__ conv_b,
    const float* __restrict__ ln1_g, const float* __restrict__ ln1_b,
    const float* __restrict__ Wl, const float* __restrict__ Wr,
    float* __restrict__ x1, float* __restrict__ gl, float* __restrict__ gr) {
    __shared__ float xt[H_DIM][XT_STRIDE];  // 18432 B; xt[h][tt] = x[tt-1][h], halo cols 0,33 = 0
    int n = blockIdx.x;
    int tid = threadIdx.x;
    int o = tid & 127, th = tid >> 7;  // thread owns out-channel o, t-range [th*16, th*16+16)

    // phase 1: load x[n] (float4, coalesced) -> transposed LDS with halo
    const float4* xv4 = (const float4*)(x + n * T_STEPS * H_DIM);
    for (int i4 = tid; i4 < T_STEPS * H_DIM / 4; i4 += 256) {
        float4 v = xv4[i4];
        int t = (i4 * 4) >> 7, h = (i4 * 4) & 127;
        xt[h][t + 1] = v.x; xt[h + 1][t + 1] = v.y;
        xt[h + 2][t + 1] = v.z; xt[h + 3][t + 1] = v.w;
    }
    if (tid < 128) { xt[tid][0] = 0.f; xt[tid][33] = 0.f; }
    __syncthreads();

    // phase 2: conv1d K=3 'SAME'. window reads: 4x b128 + 1x b64, broadcast, no bounds checks
    float acc[16];
    float bo = conv_b[o];
#pragma unroll
    for (int j = 0; j < 16; ++j) acc[j] = bo;
    for (int hi = 0; hi < H_DIM; ++hi) {
        float w0 = wt[(0 * 128 + hi) * 128 + o];
        float w1 = wt[(1 * 128 + hi) * 128 + o];
        float w2 = wt[(2 * 128 + hi) * 128 + o];
        const float* row = &xt[hi][th * 16];
        float4 a0 = *(const float4*)(row);
        float4 a1 = *(const float4*)(row + 4);
        float4 a2 = *(const float4*)(row + 8);
        float4 a3 = *(const float4*)(row + 12);
        float2 a4 = *(const float2*)(row + 16);
        float xv[18] = {a0.x, a0.y, a0.z, a0.w, a1.x, a1.y, a1.z, a1.w,
                        a2.x, a2.y, a2.z, a2.w, a3.x, a3.y, a3.z, a3.w, a4.x, a4.y};
#pragma unroll
        for (int j = 0; j < 16; ++j) acc[j] += w0 * xv[j] + w1 * xv[j + 1] + w2 * xv[j + 2];
    }
    __syncthreads();  // all conv reads of xt complete

    // phase 3: residual r = x + y (read old x at halo offset, then write r shifted to col t)
    float r[16];
#pragma unroll
    for (int j = 0; j < 16; ++j) r[j] = xt[o][th * 16 + j + 1] + acc[j];
    __syncthreads();
#pragma unroll
    for (int j = 0; j < 16; ++j) xt[o][th * 16 + j] = r[j];
    __syncthreads();

    // phase 4: LN1 over H per t (4 waves, in-place xt -> x1), also write x1 to global
    int wv = tid >> 6, lane = tid & 63;
    for (int t = wv; t < T_STEPS; t += 4) {
        float r0 = xt[lane][t], r1 = xt[lane + 64][t];
        float s = r0 + r1, s2 = r0 * r0 + r1 * r1;
#pragma unroll
        for (int mm = 1; mm < 64; mm <<= 1) {
            s += __shfl_xor(s, mm);
            s2 += __shfl_xor(s2, mm);
        }
        float mean = s * (1.f / 128.f);
        float var = s2 * (1.f / 128.f) - mean * mean;
        float rs = rsqrtf(var + LN_EPS);
        float o0 = (r0 - mean) * rs * ln1_g[lane] + ln1_b[lane];
        float o1 = (r1 - mean) * rs * ln1_g[lane + 64] + ln1_b[lane + 64];
        xt[lane][t] = o0;
        xt[lane + 64][t] = o1;
        x1[(n * T_STEPS + t) * H_DIM + lane] = o0;
        x1[(n * T_STEPS + t) * H_DIM + lane + 64] = o1;
    }
    __syncthreads();

    // phase 5: gl/gr GEMMs; xt now holds x1 transposed [h][t]
    float accl[16], accr[16];
#pragma unroll
    for (int j = 0; j < 16; ++j) { accl[j] = 0.f; accr[j] = 0.f; }
    for (int hi = 0; hi < H_DIM; ++hi) {
        float wl = Wl[hi * H_DIM + o];
        float wr = Wr[hi * H_DIM + o];
        const float* row = &xt[hi][th * 16];
        float4 b0 = *(const float4*)(row);
        float4 b1 = *(const float4*)(row + 4);
        float4 b2 = *(const float4*)(row + 8);
        float4 b3 = *(const float4*)(row + 12);
        float xv[16] = {b0.x, b0.y, b0.z, b0.w, b1.x, b1.y, b1.z, b1.w,
                        b2.x, b2.y, b2.z, b2.w, b3.x, b3.y, b3.z, b3.w};
#pragma unroll
        for (int j = 0; j < 16; ++j) {
            accl[j] += xv[j] * wl;
            accr[j] += xv[j] * wr;
        }
    }
#pragma unroll
    for (int j = 0; j < 16; ++j) {
        int t = th * 16 + j;
        gl[(t * N_NODES + n) * H_DIM + o] = accl[j];
        gr[(t * N_NODES + n) * H_DIM + o] = accr[j];
    }
}

// ---------- GATv2 per (node, graph): staged indices + 1-deep prefetch online softmax ----------
#define GAT_CH 128
__global__ __launch_bounds__(128) void k_gat(
    const float* __restrict__ gl, const float* __restrict__ gr, const float* __restrict__ ee,
    const int* __restrict__ src_arr, const int* __restrict__ csr,
    const int* __restrict__ offs, const int* __restrict__ cnt,
    const float* __restrict__ att, const float* __restrict__ gat_b,
    const float* __restrict__ x1, const float* __restrict__ ln2_g,
    const float* __restrict__ ln2_b, float* __restrict__ out) {
    int bid = blockIdx.x;  // n*32 + g  (consecutive blocks share node n -> ee/csr reuse)
    int n = bid >> 5;
    int g = bid & 31;
    int tid = threadIdx.x;  // channel h; head k = tid>>5

    __shared__ int es[GAT_CH], ss[GAT_CH];
    int off = offs[n], deg = cnt[n];
    int tot = deg + 1;  // + self-loop (last)

    float grv = gr[(g * N_NODES + n) * H_DIM + tid];
    float attv = att[tid];
    float m = -INFINITY, l = 0.f, acc = 0.f;
    const float* glg = gl + (size_t)g * N_NODES * H_DIM;

    for (int base = 0; base < tot; base += GAT_CH) {
        int c = min(GAT_CH, tot - base);
        __syncthreads();
        if (tid < c) {
            int i = base + tid;
            int e = (i < deg) ? csr[off + i] : (E_EDGES + n);
            es[tid] = e;
            ss[tid] = (i < deg) ? src_arr[e] : n;
        }
        __syncthreads();
        float glv = glg[ss[0] * H_DIM + tid];
        float eev = ee[es[0] * H_DIM + tid];
        for (int i = 0; i < c; ++i) {
            float glc = glv, eec = eev;
            if (i + 1 < c) {
                glv = glg[ss[i + 1] * H_DIM + tid];
                eev = ee[es[i + 1] * H_DIM + tid];
            }
            float sf = glc + grv + eec;
            sf = (sf >= 0.f) ? sf : NEG_SLOPE * sf;
            float p = sf * attv;
#pragma unroll
            for (int mm = 1; mm < 32; mm <<= 1) p += __shfl_xor(p, mm);  // reduce over d in head
            float mn = fmaxf(m, p);
            float sc = __expf(m - mn);  // exp(-inf)=0 on first iter
            float w = __expf(p - mn);
            l = l * sc + w;
            acc = acc * sc + w * glc;
            m = mn;
        }
    }

    float ov = acc / l + gat_b[tid];
    float rv = x1[(n * T_STEPS + g) * H_DIM + tid] + ov;

    // LN2 across 128 threads (2 waves)
    __shared__ float red[4];
    float s1 = rv, s2v = rv * rv;
#pragma unroll
    for (int mm = 1; mm < 64; mm <<= 1) {
        s1 += __shfl_xor(s1, mm);
        s2v += __shfl_xor(s2v, mm);
    }
    int wave = tid >> 6, lane = tid & 63;
    if (lane == 0) { red[wave * 2] = s1; red[wave * 2 + 1] = s2v; }
    __syncthreads();
    float ts = red[0] + red[2], ts2 = red[1] + red[3];
    float mean = ts * (1.f / 128.f);
    float var = ts2 * (1.f / 128.f) - mean * mean;
    float rs = rsqrtf(var + LN_EPS);
    out[(n * T_STEPS + g) * H_DIM + tid] = (rv - mean) * rs * ln2_g[tid] + ln2_b[tid];
}

extern "C" void kernel_launch(void* const* d_in, const int* in_sizes, int n_in,
                              void* d_out, int out_size, void* d_ws, size_t ws_size,
                              hipStream_t stream) {
    const float* x         = (const float*)d_in[0];
    const int*   ei        = (const int*)d_in[1];
    const float* edge_attr = (const float*)d_in[2];
    const float* conv_w    = (const float*)d_in[3];
    const float* conv_b    = (const float*)d_in[4];
    const float* ln1_g     = (const float*)d_in[5];
    const float* ln1_b     = (const float*)d_in[6];
    const float* Wl        = (const float*)d_in[7];
    const float* Wr        = (const float*)d_in[8];
    const float* We        = (const float*)d_in[9];
    const float* att       = (const float*)d_in[10];
    const float* gat_b     = (const float*)d_in[11];
    const float* ln2_g     = (const float*)d_in[12];
    const float* ln2_b     = (const float*)d_in[13];
    float* out = (float*)d_out;

    const int* src = ei;
    const int* dst = ei + E_EDGES;

    // workspace layout (floats)
    float* wt  = (float*)d_ws;                 // 49152
    float* x1  = wt + 49152;                   // 4,096,000
    float* gl  = x1 + 4096000;                 // 4,096,000
    float* gr  = gl + 4096000;                 // 4,096,000
    float* eew = gr + 4096000;                 // 2,176,000
    float* la  = eew + 2176000;                // 16,000
    int*   cnt  = (int*)(la + 16000);          // 1000
    int*   offs = cnt + 1000;                  // 1001
    int*   csr  = offs + 1001;                 // 16000

    k_prep_w<<<192, 256, 0, stream>>>(conv_w, wt);
    hipMemsetAsync(cnt, 0, N_NODES * sizeof(int), stream);
    k_count<<<(E_EDGES + 255) / 256, 256, 0, stream>>>(dst, cnt);
    k_scan<<<1, 1024, 0, stream>>>(cnt, offs);
    k_fill<<<N_NODES, 64, 0, stream>>>(dst, offs, csr);
    k_loopattr<<<N_NODES, 64, 0, stream>>>(edge_attr, csr, offs, cnt, la);
    k_ee<<<(EP_EDGES + 1) / 2, 256, 0, stream>>>(edge_attr, la, We, eew);
    k_temporal<<<N_NODES, 256, 0, stream>>>(x, wt, conv_b, ln1_g, ln1_b, Wl, Wr, x1, gl, gr);
    k_gat<<<N_NODES * G_GRAPHS, 128, 0, stream>>>(gl, gr, eew, src, csr, offs, cnt,
                                                  att, gat_b, x1, ln2_g, ln2_b, out);
}